// Round 1
// 10705.643 us; speedup vs baseline: 1.2093x; 1.2093x over previous
//
#include <hip/hip_runtime.h>
#include <hip/hip_bf16.h>

typedef __hip_bfloat16 bf16;
typedef __bf16 bf16x8 __attribute__((ext_vector_type(8)));
typedef float f32x4 __attribute__((ext_vector_type(4)));

#define B_      256
#define S_      128
#define HID_    768
#define EMB_    128
#define FF_     3072
#define LAYERS_ 12
#define HEADS_  12
#define DH_     64
#define M_TOK   (B_ * S_)   // 32768

__device__ inline float b2f(bf16 v) { return __bfloat162float(v); }
__device__ inline bf16  f2b(float v) { return __float2bfloat16(v); }

__device__ inline float wave_sum(float v) {
#pragma unroll
  for (int o = 32; o > 0; o >>= 1) v += __shfl_xor(v, o, 64);
  return v;
}

__device__ inline float gelu_exact(float x) {
  return 0.5f * x * (1.0f + erff(x * 0.70710678118654752f));
}

__device__ inline void glds16(const bf16* g, bf16* l) {
  __builtin_amdgcn_global_load_lds(
      (const __attribute__((address_space(1))) void*)g,
      (__attribute__((address_space(3))) void*)l, 16, 0, 0);
}

__device__ inline void bar()   { asm volatile("s_barrier" ::: "memory"); }
__device__ inline void lgkm0() {
  asm volatile("s_waitcnt lgkmcnt(0)" ::: "memory");
  __builtin_amdgcn_sched_barrier(0);
}

// ---------------------------------------------------------------------------
// 256x256-tile 8-phase GEMM: C = A (MxK bf16 rm) * Bt^T (Bt NxK bf16 rm)
// + bias; mode 0: bias, mode 1: bias+gelu.
// 512 threads = 8 waves (2M x 4N). BK=64, double-buffered 128 KiB LDS.
// Counted-vmcnt pipeline (T3+T4), LDS XOR swizzle (T2), setprio (T5),
// bijective XCD swizzle (T1/m204).
// Requires: M%256==0, N%256==0, K%64==0, K>=128.
// ---------------------------------------------------------------------------
__global__ __launch_bounds__(512, 2)
void gemm256(const bf16* __restrict__ A, const bf16* __restrict__ Bt,
             const float* __restrict__ bias, bf16* __restrict__ C,
             int M, int N, int K, int mode)
{
  __shared__ __align__(16) bf16 As[2][256 * 64];
  __shared__ __align__(16) bf16 Bs[2][256 * 64];
  const int tid  = threadIdx.x;
  const int w    = tid >> 6, lane = tid & 63;
  const int wm   = w >> 2,  wn   = w & 3;

  // bijective XCD-aware swizzle (m204): consecutive tile-ids per XCD
  const int nwg = gridDim.x * gridDim.y;
  int bid = blockIdx.y * gridDim.x + blockIdx.x;
  {
    const int q = nwg >> 3, r = nwg & 7, xcd = bid & 7, off = bid >> 3;
    bid = (xcd < r ? xcd * (q + 1) : r * (q + 1) + (xcd - r) * q) + off;
  }
  const int m0 = (bid / gridDim.x) * 256;
  const int n0 = (bid % gridDim.x) * 256;

  const int NT = K >> 6;   // number of BK=64 K-tiles (even for all our shapes)

  // ---- staging geometry -------------------------------------------------
  // per half-tile (128 rows x 64 cols bf16 = 16KB): 16 wave-chunks of 1KB;
  // wave w owns chunks c0, c0+1. Lane l covers row c*8 + (l>>3),
  // 16B at slot (l&7). LDS dest is LINEAR; global src col is pre-swizzled
  // by the involution slot ^= (row&7)  (rule #21: both-sides-or-neither).
  const int c0   = w * 2;
  const int srow = c0 * 8 + (lane >> 3);
  const int scol = ((lane & 7) ^ (lane >> 3)) * 8;
  const bf16* gA0 = A  + (size_t)(m0 + srow)     * K + scol;
  const bf16* gA1 = A  + (size_t)(m0 + srow + 8) * K + scol;
  const bf16* gB0 = Bt + (size_t)(n0 + srow)     * K + scol;
  const bf16* gB1 = Bt + (size_t)(n0 + srow + 8) * K + scol;

  auto stageA = [&](int bi, int h, int kt) {
    const size_t go = (size_t)h * 128 * (size_t)K + (size_t)kt * 64;
    bf16* l = &As[bi][h * 8192 + c0 * 512];
    glds16(gA0 + go, l);
    glds16(gA1 + go, l + 512);
  };
  auto stageB = [&](int bi, int h, int kt) {
    const size_t go = (size_t)h * 128 * (size_t)K + (size_t)kt * 64;
    bf16* l = &Bs[bi][h * 8192 + c0 * 512];
    glds16(gB0 + go, l);
    glds16(gB1 + go, l + 512);
  };

  // ---- fragment reads (swizzled) ----------------------------------------
  // interleaved wave->frag map: A frag f -> rows f*32+wm*16+[0,16)
  //                             B frag g -> rows g*64+wn*16+[0,16)
  // so phases hit exactly one A-half / one B-half for ALL waves.
  const int lr = lane & 15, lk = (lane >> 4) * 8, sx = (lane & 7) << 3;
  auto rdA = [&](int bi, int f, int kk) -> bf16x8 {
    return *(const bf16x8*)&As[bi][((f * 32 + wm * 16 + lr) * 64 + kk * 32 + lk) ^ sx];
  };
  auto rdB = [&](int bi, int g, int kk) -> bf16x8 {
    return *(const bf16x8*)&Bs[bi][((g * 64 + wn * 16 + lr) * 64 + kk * 32 + lk) ^ sx];
  };

  const f32x4 zacc = {0.f, 0.f, 0.f, 0.f};
  f32x4 acc[8][4];
#pragma unroll
  for (int f = 0; f < 8; f++)
#pragma unroll
    for (int g = 0; g < 4; g++) acc[f][g] = zacc;

  // ---- prologue: oldest-first so vmcnt(4) leaves only kt1's A0,B1 in flight
  stageA(0, 0, 0);            // A0(kt0)
  stageB(0, 1, 0);            // B1(kt0)
  stageB(0, 0, 0);            // B0(kt0)
  stageA(0, 1, 0);            // A1(kt0)
  if (NT > 1) { stageA(1, 0, 1); stageB(1, 1, 1); }   // A0(kt1), B1(kt1)
  asm volatile("s_waitcnt vmcnt(4)" ::: "memory");    // kt0 fully resident
  bar();

  for (int kt = 0; kt < NT; ++kt) {
    const int bi = kt & 1, nb = bi ^ 1;
    bf16x8 af[4][2], b01[2][2], b23[2][2];

    // ---- P1: frags f0-3 (A-half0), g0-1 (B-half0) -----------------------
#pragma unroll
    for (int f = 0; f < 4; f++) { af[f][0] = rdA(bi, f, 0); af[f][1] = rdA(bi, f, 1); }
#pragma unroll
    for (int g = 0; g < 2; g++) { b01[g][0] = rdB(bi, g, 0); b01[g][1] = rdB(bi, g, 1); }
    if (kt + 1 < NT) stageB(nb, 0, kt + 1);   // B0 slot(nb) last read kt-1 P1
    bar(); lgkm0();
    __builtin_amdgcn_s_setprio(1);
#pragma unroll
    for (int f = 0; f < 4; f++)
#pragma unroll
      for (int g = 0; g < 2; g++) {
        acc[f][g] = __builtin_amdgcn_mfma_f32_16x16x32_bf16(af[f][0], b01[g][0], acc[f][g], 0, 0, 0);
        acc[f][g] = __builtin_amdgcn_mfma_f32_16x16x32_bf16(af[f][1], b01[g][1], acc[f][g], 0, 0, 0);
      }
    __builtin_amdgcn_s_setprio(0);
    bar();

    // ---- P2: f0-3 (regs reused), g2-3 (B-half1) -------------------------
#pragma unroll
    for (int g = 0; g < 2; g++) { b23[g][0] = rdB(bi, g + 2, 0); b23[g][1] = rdB(bi, g + 2, 1); }
    if (kt + 1 < NT) stageA(nb, 1, kt + 1);   // A1 slot(nb) last read kt-1 P3
    bar(); lgkm0();
    __builtin_amdgcn_s_setprio(1);
#pragma unroll
    for (int f = 0; f < 4; f++)
#pragma unroll
      for (int g = 0; g < 2; g++) {
        acc[f][g + 2] = __builtin_amdgcn_mfma_f32_16x16x32_bf16(af[f][0], b23[g][0], acc[f][g + 2], 0, 0, 0);
        acc[f][g + 2] = __builtin_amdgcn_mfma_f32_16x16x32_bf16(af[f][1], b23[g][1], acc[f][g + 2], 0, 0, 0);
      }
    __builtin_amdgcn_s_setprio(0);
    bar();

    // ---- P3: f4-7 (A-half1), g2-3 (regs reused) -------------------------
#pragma unroll
    for (int f = 0; f < 4; f++) { af[f][0] = rdA(bi, f + 4, 0); af[f][1] = rdA(bi, f + 4, 1); }
    if (kt + 2 < NT) stageA(bi, 0, kt + 2);   // A0 slot(bi) last read this-kt P1
    bar(); lgkm0();
    __builtin_amdgcn_s_setprio(1);
#pragma unroll
    for (int f = 0; f < 4; f++)
#pragma unroll
      for (int g = 0; g < 2; g++) {
        acc[f + 4][g + 2] = __builtin_amdgcn_mfma_f32_16x16x32_bf16(af[f][0], b23[g][0], acc[f + 4][g + 2], 0, 0, 0);
        acc[f + 4][g + 2] = __builtin_amdgcn_mfma_f32_16x16x32_bf16(af[f][1], b23[g][1], acc[f + 4][g + 2], 0, 0, 0);
      }
    __builtin_amdgcn_s_setprio(0);
    bar();

    // ---- P4: f4-7 (regs), g0-1 (regs) — no ds_reads ---------------------
    if (kt + 2 < NT) stageB(bi, 1, kt + 2);   // B1 slot(bi) last read this-kt P3
    // counted drain: allow the 2 newest half-tiles (kt+2's A0,B1) in flight;
    // tail must drain fully since kt+2 stagings were skipped.
    if (kt < NT - 2) asm volatile("s_waitcnt vmcnt(4)" ::: "memory");
    else             asm volatile("s_waitcnt vmcnt(0)" ::: "memory");
    bar();
    __builtin_amdgcn_s_setprio(1);
#pragma unroll
    for (int f = 0; f < 4; f++)
#pragma unroll
      for (int g = 0; g < 2; g++) {
        acc[f + 4][g] = __builtin_amdgcn_mfma_f32_16x16x32_bf16(af[f][0], b01[g][0], acc[f + 4][g], 0, 0, 0);
        acc[f + 4][g] = __builtin_amdgcn_mfma_f32_16x16x32_bf16(af[f][1], b01[g][1], acc[f + 4][g], 0, 0, 0);
      }
    __builtin_amdgcn_s_setprio(0);
    bar();
  }

  // ---- epilogue: D row=(lane>>4)*4+r, col=lane&15 per 16x16 frag --------
  const int er = (lane >> 4) * 4, ec = lane & 15;
#pragma unroll
  for (int f = 0; f < 8; f++) {
    const int row = m0 + f * 32 + wm * 16 + er;
#pragma unroll
    for (int g = 0; g < 4; g++) {
      const int col = n0 + g * 64 + wn * 16 + ec;
      const float bv = bias[col];
#pragma unroll
      for (int r = 0; r < 4; r++) {
        float v = acc[f][g][r] + bv;
        if (mode >= 1) v = gelu_exact(v);
        C[(size_t)(row + r) * N + col] = f2b(v);
      }
    }
  }
}

// ---------------------------------------------------------------------------
// legacy 128x128 GEMM — kept for proj (mode 2, K=128) and head (N=128).
// ---------------------------------------------------------------------------
__global__ __launch_bounds__(256)
void gemm_bt(const bf16* __restrict__ A, const bf16* __restrict__ Bt,
             const float* __restrict__ bias, bf16* __restrict__ C,
             int M, int N, int K, int mode)
{
  __shared__ __align__(16) bf16 As[128 * 32];
  __shared__ __align__(16) bf16 Bs[128 * 32];
  const int tid  = threadIdx.x;
  const int wave = tid >> 6, lane = tid & 63;
  const int m0 = blockIdx.y * 128, n0 = blockIdx.x * 128;

  const int ar = lane >> 2;
  const int ac = (lane & 3) * 8;
  const int c0 = wave * 2;
  const bf16* ga0 = A  + (size_t)(m0 + c0 * 16      + ar) * K + ac;
  const bf16* ga1 = A  + (size_t)(m0 + (c0+1) * 16  + ar) * K + ac;
  const bf16* gb0 = Bt + (size_t)(n0 + c0 * 16      + ar) * K + ac;
  const bf16* gb1 = Bt + (size_t)(n0 + (c0+1) * 16  + ar) * K + ac;
  bf16* lA0 = As + c0 * 512;       bf16* lA1 = As + (c0 + 1) * 512;
  bf16* lB0 = Bs + c0 * 512;       bf16* lB1 = Bs + (c0 + 1) * 512;

  const int lr = lane & 15;
  const int lk = (lane >> 4) * 8;
  const int rm = (wave >> 1) * 64;
  const int rn = (wave & 1) * 64;

  const f32x4 zacc = {0.f, 0.f, 0.f, 0.f};
  f32x4 acc[4][4];
#pragma unroll
  for (int i = 0; i < 4; i++)
#pragma unroll
    for (int j = 0; j < 4; j++) acc[i][j] = zacc;

  for (int k0 = 0; k0 < K; k0 += 32) {
    glds16(ga0 + k0, lA0);
    glds16(ga1 + k0, lA1);
    glds16(gb0 + k0, lB0);
    glds16(gb1 + k0, lB1);
    __syncthreads();
    bf16x8 af[4], bfr[4];
#pragma unroll
    for (int i = 0; i < 4; i++) af[i]  = *(const bf16x8*)&As[(rm + i * 16 + lr) * 32 + lk];
#pragma unroll
    for (int j = 0; j < 4; j++) bfr[j] = *(const bf16x8*)&Bs[(rn + j * 16 + lr) * 32 + lk];
#pragma unroll
    for (int i = 0; i < 4; i++)
#pragma unroll
      for (int j = 0; j < 4; j++)
        acc[i][j] = __builtin_amdgcn_mfma_f32_16x16x32_bf16(af[i], bfr[j], acc[i][j], 0, 0, 0);
    __syncthreads();
  }

  const int er = (lane >> 4) * 4;
  const int ec = lane & 15;
#pragma unroll
  for (int i = 0; i < 4; i++) {
    const int row = m0 + rm + i * 16 + er;
#pragma unroll
    for (int j = 0; j < 4; j++) {
      const int col = n0 + rn + j * 16 + ec;
      const float bv = bias[col];
#pragma unroll
      for (int r = 0; r < 4; r++) {
        float v = acc[i][j][r] + bv;
        if (mode >= 1) v = gelu_exact(v);
        if (mode == 2) {
          const int srow = (row + r) & (S_ - 1);
          const int i2 = col & ~1;
          const float div = expf(-9.210340371976184f * (float)i2 * (1.0f / (float)HID_));
          const float ang = (float)srow * div;
          v += (col & 1) ? cosf(ang) : sinf(ang);
        }
        C[(size_t)(row + r) * N + col] = f2b(v);
      }
    }
  }
}

// ---------------------------------------------------------------------------
// fp32 (K,N) -> bf16 (N,K) convert + transpose.  K%32==0, N%32==0. block (32,8)
// ---------------------------------------------------------------------------
__global__ __launch_bounds__(256)
void convtrans(const float* __restrict__ src, bf16* __restrict__ dst, int K, int N)
{
  __shared__ bf16 t[32][33];
  const int n0 = blockIdx.x * 32, k0 = blockIdx.y * 32;
  const int tx = threadIdx.x, ty = threadIdx.y;
#pragma unroll
  for (int i = 0; i < 4; i++)
    t[ty + i * 8][tx] = f2b(src[(size_t)(k0 + ty + i * 8) * N + n0 + tx]);
  __syncthreads();
#pragma unroll
  for (int i = 0; i < 4; i++)
    dst[(size_t)(n0 + ty + i * 8) * K + k0 + tx] = t[tx][ty + i * 8];
}

// ---------------------------------------------------------------------------
// sliding-window attention: one block per (b, head), 128 threads (one per row)
// ---------------------------------------------------------------------------
__global__ __launch_bounds__(128)
void attn_kernel(const bf16* __restrict__ qkv, bf16* __restrict__ ctx)
{
  const int bh = blockIdx.x;
  const int b = bh / HEADS_, h = bh % HEADS_;
  __shared__ __align__(16) bf16 qs[S_ * DH_];
  __shared__ __align__(16) bf16 ks[S_ * DH_];
  __shared__ __align__(16) bf16 vs[S_ * DH_];
  const int tid = threadIdx.x;
  const bf16* base = qkv + (size_t)b * S_ * (3 * HID_) + h * DH_;
  for (int it = 0; it < 8; ++it) {
    const int s = it * 16 + (tid >> 3);
    const int seg = (tid & 7) * 8;
    const size_t go = (size_t)s * (3 * HID_) + seg;
    *(uint4*)&qs[s * DH_ + seg] = *(const uint4*)&base[go];
    *(uint4*)&ks[s * DH_ + seg] = *(const uint4*)&base[go + HID_];
    *(uint4*)&vs[s * DH_ + seg] = *(const uint4*)&base[go + 2 * HID_];
  }
  __syncthreads();
  const int i = tid;
  bf16* out = ctx + (size_t)(b * S_ + i) * HID_ + h * DH_;
  if (i < 116) {
    float p[13];
    float mx = -1e30f;
    for (int jj = 0; jj < 13; jj++) {
      if (jj == 6) { p[jj] = 0.f; continue; }
      float d = 0.f;
#pragma unroll
      for (int dd = 0; dd < DH_; dd++) d += b2f(qs[i * DH_ + dd]) * b2f(ks[(i + jj) * DH_ + dd]);
      p[jj] = d * 0.125f;
      mx = fmaxf(mx, p[jj]);
    }
    float l = 0.f;
    for (int jj = 0; jj < 13; jj++) {
      if (jj == 6) { p[jj] = 0.f; continue; }
      p[jj] = expf(p[jj] - mx);
      l += p[jj];
    }
    const float inv = 1.f / l;
    float o[DH_];
#pragma unroll
    for (int dd = 0; dd < DH_; dd++) o[dd] = 0.f;
    for (int jj = 0; jj < 13; jj++) {
      if (jj == 6) continue;
      const float pj = p[jj] * inv;
#pragma unroll
      for (int dd = 0; dd < DH_; dd++) o[dd] += pj * b2f(vs[(i + jj) * DH_ + dd]);
    }
#pragma unroll
    for (int dd = 0; dd < DH_; dd++) out[dd] = f2b(o[dd]);
  } else {
#pragma unroll
    for (int dd = 0; dd < DH_; dd++) out[dd] = f2b(0.f);
  }
}

// ---------------------------------------------------------------------------
// out = LN(x + y) over 768, bf16 in/out, fp32 math.  one block per row.
// ---------------------------------------------------------------------------
__global__ __launch_bounds__(256)
void add_ln_kernel(const bf16* __restrict__ x, const bf16* __restrict__ y,
                   const float* __restrict__ g, const float* __restrict__ bta,
                   bf16* __restrict__ out)
{
  const int r = blockIdx.x, tid = threadIdx.x;
  const size_t base = (size_t)r * HID_;
  float v[3];
#pragma unroll
  for (int e = 0; e < 3; e++) {
    const int idx = tid + e * 256;
    v[e] = b2f(x[base + idx]) + b2f(y[base + idx]);
  }
  float s  = v[0] + v[1] + v[2];
  float ss = v[0] * v[0] + v[1] * v[1] + v[2] * v[2];
  s = wave_sum(s);
  ss = wave_sum(ss);
  __shared__ float red[8];
  const int wave = tid >> 6, lane = tid & 63;
  if (lane == 0) { red[wave] = s; red[4 + wave] = ss; }
  __syncthreads();
  s  = red[0] + red[1] + red[2] + red[3];
  ss = red[4] + red[5] + red[6] + red[7];
  const float mean = s * (1.f / (float)HID_);
  const float var  = ss * (1.f / (float)HID_) - mean * mean;
  const float rs = rsqrtf(var + 1e-5f);
#pragma unroll
  for (int e = 0; e < 3; e++) {
    const int idx = tid + e * 256;
    out[base + idx] = f2b((v[e] - mean) * rs * g[idx] + bta[idx]);
  }
}

// ---------------------------------------------------------------------------
// out[token] = LN(W[idx[token]]) over 128.  one wave per token, 4 tokens/block
// ---------------------------------------------------------------------------
__global__ __launch_bounds__(256)
void gather_ln128(const int* __restrict__ idx, const float* __restrict__ W,
                  const float* __restrict__ g, const float* __restrict__ bta,
                  bf16* __restrict__ out)
{
  const int token = blockIdx.x * 4 + (threadIdx.x >> 6);
  const int lane = threadIdx.x & 63;
  const int row = idx[token];
  const float* src = W + (size_t)row * 128;
  const float a = src[lane], c = src[lane + 64];
  const float s  = wave_sum(a + c);
  const float ss = wave_sum(a * a + c * c);
  const float mean = s * (1.f / 128.f);
  const float var  = ss * (1.f / 128.f) - mean * mean;
  const float rs = rsqrtf(var + 1e-5f);
  bf16* o = out + (size_t)token * 128;
  o[lane]      = f2b((a - mean) * rs * g[lane] + bta[lane]);
  o[lane + 64] = f2b((c - mean) * rs * g[lane + 64] + bta[lane + 64]);
}

__global__ __launch_bounds__(256)
void ln128_bf16(const bf16* __restrict__ in, const float* __restrict__ g,
                const float* __restrict__ bta, bf16* __restrict__ out)
{
  const int token = blockIdx.x * 4 + (threadIdx.x >> 6);
  const int lane = threadIdx.x & 63;
  const bf16* src = in + (size_t)token * 128;
  const float a = b2f(src[lane]), c = b2f(src[lane + 64]);
  const float s  = wave_sum(a + c);
  const float ss = wave_sum(a * a + c * c);
  const float mean = s * (1.f / 128.f);
  const float var  = ss * (1.f / 128.f) - mean * mean;
  const float rs = rsqrtf(var + 1e-5f);
  bf16* o = out + (size_t)token * 128;
  o[lane]      = f2b((a - mean) * rs * g[lane] + bta[lane]);
  o[lane + 64] = f2b((c - mean) * rs * g[lane + 64] + bta[lane + 64]);
}

// ---------------------------------------------------------------------------
// loss: grid (B, 2).  y==0: softplus(-mean6(out_z . preds)); y==1: softplus(+mean6(out_z . neg_e))
// ---------------------------------------------------------------------------
__global__ __launch_bounds__(256)
void loss_kernel(const bf16* __restrict__ out_z, const bf16* __restrict__ preds,
                 const bf16* __restrict__ neg_e, float* __restrict__ out)
{
  const int b = blockIdx.x;
  const int which = blockIdx.y;
  __shared__ __align__(16) bf16 zo[128 * 128];
  __shared__ __align__(16) bf16 mt[128 * 128];
  const bf16* msrc = which ? neg_e : preds;
  const uint4* gz = (const uint4*)(out_z + (size_t)b * 16384);
  const uint4* gm = (const uint4*)(msrc + (size_t)b * 16384);
  for (int it = threadIdx.x; it < 2048; it += 256) {
    ((uint4*)zo)[it] = gz[it];
    ((uint4*)mt)[it] = gm[it];
  }
  __syncthreads();
  float local = 0.f;
  for (int it = threadIdx.x; it < 232; it += 256) {
    const int i = it >> 1;
    const int sub = it & 1;
    const int c0 = i + (sub ? 7 : 0);
    const bf16* zr = &zo[i * 128];
    float accv = 0.f;
    for (int jj = 0; jj < 6; jj++) {
      const bf16* mr = &mt[(c0 + jj) * 128];
      float d = 0.f;
#pragma unroll
      for (int dd = 0; dd < 128; dd++) d += b2f(zr[dd]) * b2f(mr[dd]);
      accv += d;
    }
    const float mean = accv * (1.f / 6.f);
    const float xin = which ? mean : -mean;
    local += fmaxf(xin, 0.f) + log1pf(expf(-fabsf(xin)));
  }
  local = wave_sum(local);
  if ((threadIdx.x & 63) == 0)
    atomicAdd(out, local * (1.f / 118784.f));
}

__global__ void zero_kernel(float* p) { p[0] = 0.f; }

// ---------------------------------------------------------------------------
extern "C" void kernel_launch(void* const* d_in, const int* in_sizes, int n_in,
                              void* d_out, int out_size, void* d_ws, size_t ws_size,
                              hipStream_t stream)
{
  (void)in_sizes; (void)n_in; (void)out_size; (void)ws_size;
  const int*   seq     = (const int*)  d_in[0];
  const int*   neg_idx = (const int*)  d_in[1];
  const float* embed_W = (const float*)d_in[2];
  const float* embed_g = (const float*)d_in[3];
  const float* embed_b = (const float*)d_in[4];
  const float* proj_W  = (const float*)d_in[5];
  const float* proj_b  = (const float*)d_in[6];
  const float* qkv_W   = (const float*)d_in[7];
  const float* qkv_b   = (const float*)d_in[8];
  const float* ao_W    = (const float*)d_in[9];
  const float* ao_b    = (const float*)d_in[10];
  const float* ln1_g   = (const float*)d_in[11];
  const float* ln1_b   = (const float*)d_in[12];
  const float* ff1_W   = (const float*)d_in[13];
  const float* ff1_b   = (const float*)d_in[14];
  const float* ff2_W   = (const float*)d_in[15];
  const float* ff2_b   = (const float*)d_in[16];
  const float* ln2_g   = (const float*)d_in[17];
  const float* ln2_b   = (const float*)d_in[18];
  const float* head_W  = (const float*)d_in[19];
  const float* head_b  = (const float*)d_in[20];
  const float* head_g  = (const float*)d_in[21];
  const float* head_bt = (const float*)d_in[22];
  const float* oemb_W  = (const float*)d_in[23];
  const float* oemb_g  = (const float*)d_in[24];
  const float* oemb_b  = (const float*)d_in[25];
  float* out = (float*)d_out;

  char* ws = (char*)d_ws;
  size_t off = 0;
  auto alloc = [&](size_t bytes) -> char* {
    char* p = ws + off;
    off += (bytes + 255) & ~(size_t)255;
    return p;
  };
  bf16* wt_qkv  = (bf16*)alloc((size_t)2304 * 768 * 2);
  bf16* wt_ao   = (bf16*)alloc((size_t)768 * 768 * 2);
  bf16* wt_ff1  = (bf16*)alloc((size_t)3072 * 768 * 2);
  bf16* wt_ff2  = (bf16*)alloc((size_t)768 * 3072 * 2);
  bf16* wt_proj = (bf16*)alloc((size_t)768 * 128 * 2);
  bf16* wt_head = (bf16*)alloc((size_t)128 * 768 * 2);
  bf16* zbuf    = (bf16*)alloc((size_t)M_TOK * 128 * 2);
  bf16* x       = (bf16*)alloc((size_t)M_TOK * 768 * 2);
  bf16* big     = (bf16*)alloc((size_t)M_TOK * 3072 * 2);  // qkv, then h
  bf16* ctx     = (bf16*)alloc((size_t)M_TOK * 768 * 2);
  bf16* ybuf    = (bf16*)alloc((size_t)M_TOK * 768 * 2);
  bf16* p0      = (bf16*)alloc((size_t)M_TOK * 128 * 2);
  bf16* preds   = (bf16*)alloc((size_t)M_TOK * 128 * 2);
  bf16* outz    = (bf16*)alloc((size_t)M_TOK * 128 * 2);
  bf16* nege    = (bf16*)alloc((size_t)M_TOK * 128 * 2);

  const dim3 tb(32, 8);

  convtrans<<<dim3(768 / 32, 128 / 32), tb, 0, stream>>>(proj_W, wt_proj, 128, 768);
  convtrans<<<dim3(128 / 32, 768 / 32), tb, 0, stream>>>(head_W, wt_head, 768, 128);

  gather_ln128<<<M_TOK / 4, 256, 0, stream>>>(seq, embed_W, embed_g, embed_b, zbuf);
  gemm_bt<<<dim3(768 / 128, M_TOK / 128), 256, 0, stream>>>(zbuf, wt_proj, proj_b, x,
                                                            M_TOK, 768, 128, 2);

  for (int l = 0; l < LAYERS_; ++l) {
    convtrans<<<dim3(2304 / 32, 768 / 32), tb, 0, stream>>>(qkv_W + (size_t)l * 768 * 2304, wt_qkv, 768, 2304);
    convtrans<<<dim3(768 / 32, 768 / 32), tb, 0, stream>>>(ao_W + (size_t)l * 768 * 768, wt_ao, 768, 768);
    convtrans<<<dim3(3072 / 32, 768 / 32), tb, 0, stream>>>(ff1_W + (size_t)l * 768 * 3072, wt_ff1, 768, 3072);
    convtrans<<<dim3(768 / 32, 3072 / 32), tb, 0, stream>>>(ff2_W + (size_t)l * 3072 * 768, wt_ff2, 3072, 768);

    gemm256<<<dim3(2304 / 256, M_TOK / 256), 512, 0, stream>>>(x, wt_qkv, qkv_b + l * 2304, big,
                                                               M_TOK, 2304, 768, 0);
    attn_kernel<<<B_ * HEADS_, 128, 0, stream>>>(big, ctx);
    gemm256<<<dim3(768 / 256, M_TOK / 256), 512, 0, stream>>>(ctx, wt_ao, ao_b + l * 768, ybuf,
                                                              M_TOK, 768, 768, 0);
    add_ln_kernel<<<M_TOK, 256, 0, stream>>>(x, ybuf, ln1_g + l * 768, ln1_b + l * 768, x);
    gemm256<<<dim3(3072 / 256, M_TOK / 256), 512, 0, stream>>>(x, wt_ff1, ff1_b + l * 3072, big,
                                                               M_TOK, 3072, 768, 1);
    gemm256<<<dim3(768 / 256, M_TOK / 256), 512, 0, stream>>>(big, wt_ff2, ff2_b + l * 768, ybuf,
                                                              M_TOK, 768, 3072, 0);
    add_ln_kernel<<<M_TOK, 256, 0, stream>>>(x, ybuf, ln2_g + l * 768, ln2_b + l * 768, x);
  }

  gemm_bt<<<dim3(1, M_TOK / 128), 256, 0, stream>>>(x, wt_head, head_b, p0, M_TOK, 128, 768, 0);
  ln128_bf16<<<M_TOK / 4, 256, 0, stream>>>(p0, head_g, head_bt, preds);
  gather_ln128<<<M_TOK / 4, 256, 0, stream>>>(seq, oemb_W, oemb_g, oemb_b, outz);
  gather_ln128<<<M_TOK / 4, 256, 0, stream>>>(neg_idx, oemb_W, oemb_g, oemb_b, nege);
  zero_kernel<<<1, 1, 0, stream>>>(out);
  loss_kernel<<<dim3(B_, 2), 256, 0, stream>>>(outz, preds, nege, out);
}

// Round 2
// 10323.384 us; speedup vs baseline: 1.2540x; 1.0370x over previous
//
#include <hip/hip_runtime.h>
#include <hip/hip_bf16.h>

typedef __hip_bfloat16 bf16;
typedef __bf16 bf16x8 __attribute__((ext_vector_type(8)));
typedef float f32x4 __attribute__((ext_vector_type(4)));

#define B_      256
#define S_      128
#define HID_    768
#define EMB_    128
#define FF_     3072
#define LAYERS_ 12
#define HEADS_  12
#define DH_     64
#define M_TOK   (B_ * S_)   // 32768

__device__ inline float b2f(bf16 v) { return __bfloat162float(v); }
__device__ inline bf16  f2b(float v) { return __float2bfloat16(v); }

__device__ inline float wave_sum(float v) {
#pragma unroll
  for (int o = 32; o > 0; o >>= 1) v += __shfl_xor(v, o, 64);
  return v;
}

// gelu via A&S 7.1.26 erf minimax (|err|<=1.5e-7; sub-bf16-ulp)
__device__ inline float gelu_fast(float x) {
  const float s  = x * 0.70710678118654752f;
  const float ax = fabsf(s);
  const float t  = 1.0f / fmaf(0.3275911f, ax, 1.0f);
  float y = fmaf(t, 1.061405429f, -1.453152027f);
  y = fmaf(t, y, 1.421413741f);
  y = fmaf(t, y, -0.284496736f);
  y = fmaf(t, y, 0.254829592f);
  y = y * t;
  const float e  = __expf(-ax * ax);
  float er = 1.0f - y * e;
  er = copysignf(er, s);
  return 0.5f * x * (1.0f + er);
}

__device__ inline void glds16(const bf16* g, bf16* l) {
  __builtin_amdgcn_global_load_lds(
      (const __attribute__((address_space(1))) void*)g,
      (__attribute__((address_space(3))) void*)l, 16, 0, 0);
}

__device__ inline void bar()   { asm volatile("s_barrier" ::: "memory"); }
__device__ inline void lgkm0() {
  asm volatile("s_waitcnt lgkmcnt(0)" ::: "memory");
  __builtin_amdgcn_sched_barrier(0);
}

// ---------------------------------------------------------------------------
// Persistent 256x256-tile 8-phase GEMM: C = A (MxK bf16 rm) * Bt^T + bias;
// mode 0: bias, mode 1: bias+gelu.
// grid = 256 blocks (1/CU), 512 threads = 8 waves (2M x 4N). BK=64,
// double-buffered 128 KiB LDS. The counted-vmcnt pipeline (T3+T4) runs
// CONTINUOUSLY across the block's tile list: prefetch for tile t+1's first
// K-tiles issues during tile t's last K-tiles, so the bias/gelu/store
// epilogue overlaps the next tile's global loads (1 block/CU means nothing
// else can hide it). Tile list is XCD-chunked for L2 locality.
// Requires: M%256==0, N%256==0, K%128==0, (M/256)*(N/256)%8==0.
// ---------------------------------------------------------------------------
__global__ __launch_bounds__(512, 2)
void gemm256p(const bf16* __restrict__ A, const bf16* __restrict__ Bt,
              const float* __restrict__ bias, bf16* __restrict__ C,
              int M, int N, int K, int mode)
{
  __shared__ __align__(16) bf16 As[2][256 * 64];
  __shared__ __align__(16) bf16 Bs[2][256 * 64];
  const int tid  = threadIdx.x;
  const int w    = tid >> 6, lane = tid & 63;
  const int wm   = w >> 2,  wn   = w & 3;

  // ---- persistent tile list (XCD-chunked) -------------------------------
  const int gx  = N >> 8;
  const int T   = (M >> 8) * gx;
  const int Cx  = T >> 3;                 // tiles per XCD
  const int xcd = blockIdx.x & 7, ci = blockIdx.x >> 3;
  if (ci >= Cx) return;
  const int R = (Cx - 1 - ci) / 32 + 1;   // tiles this block owns
  const int NT = K >> 6;
  const int U  = R * NT;                  // total flattened K-steps

  int jc = 0, kt = 0;
  const int t0 = xcd * Cx + ci;
  int m0 = (t0 / gx) << 8, n0 = (t0 % gx) << 8;
  int m0n = 0, n0n = 0;
  if (R > 1) { const int tn = t0 + 32; m0n = (tn / gx) << 8; n0n = (tn % gx) << 8; }

  // ---- staging geometry (linear LDS dest, inverse-swizzled global src) ---
  const int c0   = w * 2;
  const int srow = c0 * 8 + (lane >> 3);
  const int scol = ((lane & 7) ^ (lane >> 3)) * 8;

  auto stA = [&](int bi, int h, int m0t, int ktt) {
    const bf16* g = A + (size_t)(m0t + h * 128 + srow) * K + (ktt * 64 + scol);
    bf16* l = &As[bi][h * 8192 + c0 * 512];
    glds16(g, l);
    glds16(g + (size_t)8 * K, l + 512);
  };
  auto stB = [&](int bi, int h, int n0t, int ktt) {
    const bf16* g = Bt + (size_t)(n0t + h * 128 + srow) * K + (ktt * 64 + scol);
    bf16* l = &Bs[bi][h * 8192 + c0 * 512];
    glds16(g, l);
    glds16(g + (size_t)8 * K, l + 512);
  };

  // ---- fragment reads (swizzled) ----------------------------------------
  const int lr = lane & 15, lk = (lane >> 4) * 8, sx = (lane & 7) << 3;
  auto rdA = [&](int bi, int f, int kk) -> bf16x8 {
    return *(const bf16x8*)&As[bi][((f * 32 + wm * 16 + lr) * 64 + kk * 32 + lk) ^ sx];
  };
  auto rdB = [&](int bi, int g, int kk) -> bf16x8 {
    return *(const bf16x8*)&Bs[bi][((g * 64 + wn * 16 + lr) * 64 + kk * 32 + lk) ^ sx];
  };

  const f32x4 zacc = {0.f, 0.f, 0.f, 0.f};
  f32x4 acc[8][4];
#pragma unroll
  for (int f = 0; f < 8; f++)
#pragma unroll
    for (int g = 0; g < 4; g++) acc[f][g] = zacc;

  const int er = (lane >> 4) * 4, ec = lane & 15;

  // ---- prologue: u0 fully + u1's A0,B1 (oldest-first) -------------------
  stA(0, 0, m0, 0); stB(0, 1, n0, 0); stB(0, 0, n0, 0); stA(0, 1, m0, 0);
  stA(1, 0, m0, 1); stB(1, 1, n0, 1);
  asm volatile("s_waitcnt vmcnt(4)" ::: "memory");   // u0 resident
  bar();

  for (int u = 0; u < U; ++u) {
    const int bi = u & 1, nb = bi ^ 1;
    const bool h1 = (u + 1 < U), h2 = (u + 2 < U);
    // flattened targets for u+1 / u+2 (may roll into next tile)
    int kt1 = kt + 1, m01 = m0, n01 = n0;
    if (kt1 == NT) { kt1 = 0; m01 = m0n; n01 = n0n; }
    int kt2 = kt + 2, m02 = m0, n02 = n0;
    if (kt2 >= NT) { kt2 -= NT; m02 = m0n; n02 = n0n; }

    bf16x8 af[4][2], b01[2][2], b23[2][2];

    // ---- P1: f0-3 (A-half0), g0-1 (B-half0) -----------------------------
#pragma unroll
    for (int f = 0; f < 4; f++) { af[f][0] = rdA(bi, f, 0); af[f][1] = rdA(bi, f, 1); }
#pragma unroll
    for (int g = 0; g < 2; g++) { b01[g][0] = rdB(bi, g, 0); b01[g][1] = rdB(bi, g, 1); }
    if (h1) stB(nb, 0, n01, kt1);
    bar(); lgkm0();
    __builtin_amdgcn_s_setprio(1);
#pragma unroll
    for (int f = 0; f < 4; f++)
#pragma unroll
      for (int g = 0; g < 2; g++) {
        acc[f][g] = __builtin_amdgcn_mfma_f32_16x16x32_bf16(af[f][0], b01[g][0], acc[f][g], 0, 0, 0);
        acc[f][g] = __builtin_amdgcn_mfma_f32_16x16x32_bf16(af[f][1], b01[g][1], acc[f][g], 0, 0, 0);
      }
    __builtin_amdgcn_s_setprio(0);
    bar();

    // ---- P2: f0-3 (regs), g2-3 (B-half1) --------------------------------
#pragma unroll
    for (int g = 0; g < 2; g++) { b23[g][0] = rdB(bi, g + 2, 0); b23[g][1] = rdB(bi, g + 2, 1); }
    if (h1) stA(nb, 1, m01, kt1);
    bar(); lgkm0();
    __builtin_amdgcn_s_setprio(1);
#pragma unroll
    for (int f = 0; f < 4; f++)
#pragma unroll
      for (int g = 0; g < 2; g++) {
        acc[f][g + 2] = __builtin_amdgcn_mfma_f32_16x16x32_bf16(af[f][0], b23[g][0], acc[f][g + 2], 0, 0, 0);
        acc[f][g + 2] = __builtin_amdgcn_mfma_f32_16x16x32_bf16(af[f][1], b23[g][1], acc[f][g + 2], 0, 0, 0);
      }
    __builtin_amdgcn_s_setprio(0);
    bar();

    // ---- P3: f4-7 (A-half1), g2-3 (regs) --------------------------------
#pragma unroll
    for (int f = 0; f < 4; f++) { af[f][0] = rdA(bi, f + 4, 0); af[f][1] = rdA(bi, f + 4, 1); }
    if (h2) stA(bi, 0, m02, kt2);
    bar(); lgkm0();
    __builtin_amdgcn_s_setprio(1);
#pragma unroll
    for (int f = 0; f < 4; f++)
#pragma unroll
      for (int g = 0; g < 2; g++) {
        acc[f + 4][g + 2] = __builtin_amdgcn_mfma_f32_16x16x32_bf16(af[f][0], b23[g][0], acc[f + 4][g + 2], 0, 0, 0);
        acc[f + 4][g + 2] = __builtin_amdgcn_mfma_f32_16x16x32_bf16(af[f][1], b23[g][1], acc[f + 4][g + 2], 0, 0, 0);
      }
    __builtin_amdgcn_s_setprio(0);
    bar();

    // ---- P4: f4-7 x g0-1 (all regs) + counted drain ---------------------
    if (h2) stB(bi, 1, n02, kt2);
    if (u < U - 2) asm volatile("s_waitcnt vmcnt(4)" ::: "memory");
    else           asm volatile("s_waitcnt vmcnt(0)" ::: "memory");
    bar();
    __builtin_amdgcn_s_setprio(1);
#pragma unroll
    for (int f = 0; f < 4; f++)
#pragma unroll
      for (int g = 0; g < 2; g++) {
        acc[f + 4][g] = __builtin_amdgcn_mfma_f32_16x16x32_bf16(af[f][0], b01[g][0], acc[f + 4][g], 0, 0, 0);
        acc[f + 4][g] = __builtin_amdgcn_mfma_f32_16x16x32_bf16(af[f][1], b01[g][1], acc[f + 4][g], 0, 0, 0);
      }
    __builtin_amdgcn_s_setprio(0);
    bar();

    // ---- tile boundary: epilogue overlaps next tile's in-flight loads ---
    if (++kt == NT) {
#pragma unroll
      for (int f = 0; f < 8; f++) {
        const int row = m0 + f * 32 + wm * 16 + er;
#pragma unroll
        for (int g = 0; g < 4; g++) {
          const int col = n0 + g * 64 + wn * 16 + ec;
          const float bv = bias[col];
#pragma unroll
          for (int r = 0; r < 4; r++) {
            float v = acc[f][g][r] + bv;
            if (mode >= 1) v = gelu_fast(v);
            C[(size_t)(row + r) * N + col] = f2b(v);
          }
          acc[f][g] = zacc;
        }
      }
      kt = 0; ++jc;
      m0 = m0n; n0 = n0n;
      if (jc + 1 < R) {
        const int tn = xcd * Cx + (jc + 1) * 32 + ci;
        m0n = (tn / gx) << 8; n0n = (tn % gx) << 8;
      }
    }
  }
}

// ---------------------------------------------------------------------------
// legacy 128x128 GEMM — kept for proj (mode 2, K=128) and head (N=128).
// ---------------------------------------------------------------------------
__global__ __launch_bounds__(256)
void gemm_bt(const bf16* __restrict__ A, const bf16* __restrict__ Bt,
             const float* __restrict__ bias, bf16* __restrict__ C,
             int M, int N, int K, int mode)
{
  __shared__ __align__(16) bf16 As[128 * 32];
  __shared__ __align__(16) bf16 Bs[128 * 32];
  const int tid  = threadIdx.x;
  const int wave = tid >> 6, lane = tid & 63;
  const int m0 = blockIdx.y * 128, n0 = blockIdx.x * 128;

  const int ar = lane >> 2;
  const int ac = (lane & 3) * 8;
  const int c0 = wave * 2;
  const bf16* ga0 = A  + (size_t)(m0 + c0 * 16      + ar) * K + ac;
  const bf16* ga1 = A  + (size_t)(m0 + (c0+1) * 16  + ar) * K + ac;
  const bf16* gb0 = Bt + (size_t)(n0 + c0 * 16      + ar) * K + ac;
  const bf16* gb1 = Bt + (size_t)(n0 + (c0+1) * 16  + ar) * K + ac;
  bf16* lA0 = As + c0 * 512;       bf16* lA1 = As + (c0 + 1) * 512;
  bf16* lB0 = Bs + c0 * 512;       bf16* lB1 = Bs + (c0 + 1) * 512;

  const int lr = lane & 15;
  const int lk = (lane >> 4) * 8;
  const int rm = (wave >> 1) * 64;
  const int rn = (wave & 1) * 64;

  const f32x4 zacc = {0.f, 0.f, 0.f, 0.f};
  f32x4 acc[4][4];
#pragma unroll
  for (int i = 0; i < 4; i++)
#pragma unroll
    for (int j = 0; j < 4; j++) acc[i][j] = zacc;

  for (int k0 = 0; k0 < K; k0 += 32) {
    glds16(ga0 + k0, lA0);
    glds16(ga1 + k0, lA1);
    glds16(gb0 + k0, lB0);
    glds16(gb1 + k0, lB1);
    __syncthreads();
    bf16x8 af[4], bfr[4];
#pragma unroll
    for (int i = 0; i < 4; i++) af[i]  = *(const bf16x8*)&As[(rm + i * 16 + lr) * 32 + lk];
#pragma unroll
    for (int j = 0; j < 4; j++) bfr[j] = *(const bf16x8*)&Bs[(rn + j * 16 + lr) * 32 + lk];
#pragma unroll
    for (int i = 0; i < 4; i++)
#pragma unroll
      for (int j = 0; j < 4; j++)
        acc[i][j] = __builtin_amdgcn_mfma_f32_16x16x32_bf16(af[i], bfr[j], acc[i][j], 0, 0, 0);
    __syncthreads();
  }

  const int er = (lane >> 4) * 4;
  const int ec = lane & 15;
#pragma unroll
  for (int i = 0; i < 4; i++) {
    const int row = m0 + rm + i * 16 + er;
#pragma unroll
    for (int j = 0; j < 4; j++) {
      const int col = n0 + rn + j * 16 + ec;
      const float bv = bias[col];
#pragma unroll
      for (int r = 0; r < 4; r++) {
        float v = acc[i][j][r] + bv;
        if (mode >= 1) v = gelu_fast(v);
        if (mode == 2) {
          const int srow = (row + r) & (S_ - 1);
          const int i2 = col & ~1;
          const float div = expf(-9.210340371976184f * (float)i2 * (1.0f / (float)HID_));
          const float ang = (float)srow * div;
          v += (col & 1) ? cosf(ang) : sinf(ang);
        }
        C[(size_t)(row + r) * N + col] = f2b(v);
      }
    }
  }
}

// ---------------------------------------------------------------------------
// fp32 (K,N) -> bf16 (N,K) convert + transpose.  K%32==0, N%32==0. block (32,8)
// ---------------------------------------------------------------------------
__global__ __launch_bounds__(256)
void convtrans(const float* __restrict__ src, bf16* __restrict__ dst, int K, int N)
{
  __shared__ bf16 t[32][33];
  const int n0 = blockIdx.x * 32, k0 = blockIdx.y * 32;
  const int tx = threadIdx.x, ty = threadIdx.y;
#pragma unroll
  for (int i = 0; i < 4; i++)
    t[ty + i * 8][tx] = f2b(src[(size_t)(k0 + ty + i * 8) * N + n0 + tx]);
  __syncthreads();
#pragma unroll
  for (int i = 0; i < 4; i++)
    dst[(size_t)(n0 + ty + i * 8) * K + k0 + tx] = t[tx][ty + i * 8];
}

// ---------------------------------------------------------------------------
// sliding-window attention: one block per (b, head), 128 threads (one per row)
// ---------------------------------------------------------------------------
__global__ __launch_bounds__(128)
void attn_kernel(const bf16* __restrict__ qkv, bf16* __restrict__ ctx)
{
  const int bh = blockIdx.x;
  const int b = bh / HEADS_, h = bh % HEADS_;
  __shared__ __align__(16) bf16 qs[S_ * DH_];
  __shared__ __align__(16) bf16 ks[S_ * DH_];
  __shared__ __align__(16) bf16 vs[S_ * DH_];
  const int tid = threadIdx.x;
  const bf16* base = qkv + (size_t)b * S_ * (3 * HID_) + h * DH_;
  for (int it = 0; it < 8; ++it) {
    const int s = it * 16 + (tid >> 3);
    const int seg = (tid & 7) * 8;
    const size_t go = (size_t)s * (3 * HID_) + seg;
    *(uint4*)&qs[s * DH_ + seg] = *(const uint4*)&base[go];
    *(uint4*)&ks[s * DH_ + seg] = *(const uint4*)&base[go + HID_];
    *(uint4*)&vs[s * DH_ + seg] = *(const uint4*)&base[go + 2 * HID_];
  }
  __syncthreads();
  const int i = tid;
  bf16* out = ctx + (size_t)(b * S_ + i) * HID_ + h * DH_;
  if (i < 116) {
    float p[13];
    float mx = -1e30f;
    for (int jj = 0; jj < 13; jj++) {
      if (jj == 6) { p[jj] = 0.f; continue; }
      float d = 0.f;
#pragma unroll
      for (int dd = 0; dd < DH_; dd++) d += b2f(qs[i * DH_ + dd]) * b2f(ks[(i + jj) * DH_ + dd]);
      p[jj] = d * 0.125f;
      mx = fmaxf(mx, p[jj]);
    }
    float l = 0.f;
    for (int jj = 0; jj < 13; jj++) {
      if (jj == 6) { p[jj] = 0.f; continue; }
      p[jj] = expf(p[jj] - mx);
      l += p[jj];
    }
    const float inv = 1.f / l;
    float o[DH_];
#pragma unroll
    for (int dd = 0; dd < DH_; dd++) o[dd] = 0.f;
    for (int jj = 0; jj < 13; jj++) {
      if (jj == 6) continue;
      const float pj = p[jj] * inv;
#pragma unroll
      for (int dd = 0; dd < DH_; dd++) o[dd] += pj * b2f(vs[(i + jj) * DH_ + dd]);
    }
#pragma unroll
    for (int dd = 0; dd < DH_; dd++) out[dd] = f2b(o[dd]);
  } else {
#pragma unroll
    for (int dd = 0; dd < DH_; dd++) out[dd] = f2b(0.f);
  }
}

// ---------------------------------------------------------------------------
// out = LN(x + y) over 768, bf16 in/out, fp32 math.  one block per row.
// ---------------------------------------------------------------------------
__global__ __launch_bounds__(256)
void add_ln_kernel(const bf16* __restrict__ x, const bf16* __restrict__ y,
                   const float* __restrict__ g, const float* __restrict__ bta,
                   bf16* __restrict__ out)
{
  const int r = blockIdx.x, tid = threadIdx.x;
  const size_t base = (size_t)r * HID_;
  float v[3];
#pragma unroll
  for (int e = 0; e < 3; e++) {
    const int idx = tid + e * 256;
    v[e] = b2f(x[base + idx]) + b2f(y[base + idx]);
  }
  float s  = v[0] + v[1] + v[2];
  float ss = v[0] * v[0] + v[1] * v[1] + v[2] * v[2];
  s = wave_sum(s);
  ss = wave_sum(ss);
  __shared__ float red[8];
  const int wave = tid >> 6, lane = tid & 63;
  if (lane == 0) { red[wave] = s; red[4 + wave] = ss; }
  __syncthreads();
  s  = red[0] + red[1] + red[2] + red[3];
  ss = red[4] + red[5] + red[6] + red[7];
  const float mean = s * (1.f / (float)HID_);
  const float var  = ss * (1.f / (float)HID_) - mean * mean;
  const float rs = rsqrtf(var + 1e-5f);
#pragma unroll
  for (int e = 0; e < 3; e++) {
    const int idx = tid + e * 256;
    out[base + idx] = f2b((v[e] - mean) * rs * g[idx] + bta[idx]);
  }
}

// ---------------------------------------------------------------------------
// out[token] = LN(W[idx[token]]) over 128.  one wave per token, 4 tokens/block
// ---------------------------------------------------------------------------
__global__ __launch_bounds__(256)
void gather_ln128(const int* __restrict__ idx, const float* __restrict__ W,
                  const float* __restrict__ g, const float* __restrict__ bta,
                  bf16* __restrict__ out)
{
  const int token = blockIdx.x * 4 + (threadIdx.x >> 6);
  const int lane = threadIdx.x & 63;
  const int row = idx[token];
  const float* src = W + (size_t)row * 128;
  const float a = src[lane], c = src[lane + 64];
  const float s  = wave_sum(a + c);
  const float ss = wave_sum(a * a + c * c);
  const float mean = s * (1.f / 128.f);
  const float var  = ss * (1.f / 128.f) - mean * mean;
  const float rs = rsqrtf(var + 1e-5f);
  bf16* o = out + (size_t)token * 128;
  o[lane]      = f2b((a - mean) * rs * g[lane] + bta[lane]);
  o[lane + 64] = f2b((c - mean) * rs * g[lane + 64] + bta[lane + 64]);
}

__global__ __launch_bounds__(256)
void ln128_bf16(const bf16* __restrict__ in, const float* __restrict__ g,
                const float* __restrict__ bta, bf16* __restrict__ out)
{
  const int token = blockIdx.x * 4 + (threadIdx.x >> 6);
  const int lane = threadIdx.x & 63;
  const bf16* src = in + (size_t)token * 128;
  const float a = b2f(src[lane]), c = b2f(src[lane + 64]);
  const float s  = wave_sum(a + c);
  const float ss = wave_sum(a * a + c * c);
  const float mean = s * (1.f / 128.f);
  const float var  = ss * (1.f / 128.f) - mean * mean;
  const float rs = rsqrtf(var + 1e-5f);
  bf16* o = out + (size_t)token * 128;
  o[lane]      = f2b((a - mean) * rs * g[lane] + bta[lane]);
  o[lane + 64] = f2b((c - mean) * rs * g[lane + 64] + bta[lane + 64]);
}

// ---------------------------------------------------------------------------
// loss: grid (B, 2).  y==0: softplus(-mean6(out_z . preds)); y==1: softplus(+mean6(out_z . neg_e))
// ---------------------------------------------------------------------------
__global__ __launch_bounds__(256)
void loss_kernel(const bf16* __restrict__ out_z, const bf16* __restrict__ preds,
                 const bf16* __restrict__ neg_e, float* __restrict__ out)
{
  const int b = blockIdx.x;
  const int which = blockIdx.y;
  __shared__ __align__(16) bf16 zo[128 * 128];
  __shared__ __align__(16) bf16 mt[128 * 128];
  const bf16* msrc = which ? neg_e : preds;
  const uint4* gz = (const uint4*)(out_z + (size_t)b * 16384);
  const uint4* gm = (const uint4*)(msrc + (size_t)b * 16384);
  for (int it = threadIdx.x; it < 2048; it += 256) {
    ((uint4*)zo)[it] = gz[it];
    ((uint4*)mt)[it] = gm[it];
  }
  __syncthreads();
  float local = 0.f;
  for (int it = threadIdx.x; it < 232; it += 256) {
    const int i = it >> 1;
    const int sub = it & 1;
    const int c0 = i + (sub ? 7 : 0);
    const bf16* zr = &zo[i * 128];
    float accv = 0.f;
    for (int jj = 0; jj < 6; jj++) {
      const bf16* mr = &mt[(c0 + jj) * 128];
      float d = 0.f;
#pragma unroll
      for (int dd = 0; dd < 128; dd++) d += b2f(zr[dd]) * b2f(mr[dd]);
      accv += d;
    }
    const float mean = accv * (1.f / 6.f);
    const float xin = which ? mean : -mean;
    local += fmaxf(xin, 0.f) + log1pf(expf(-fabsf(xin)));
  }
  local = wave_sum(local);
  if ((threadIdx.x & 63) == 0)
    atomicAdd(out, local * (1.f / 118784.f));
}

__global__ void zero_kernel(float* p) { p[0] = 0.f; }

// ---------------------------------------------------------------------------
extern "C" void kernel_launch(void* const* d_in, const int* in_sizes, int n_in,
                              void* d_out, int out_size, void* d_ws, size_t ws_size,
                              hipStream_t stream)
{
  (void)in_sizes; (void)n_in; (void)out_size; (void)ws_size;
  const int*   seq     = (const int*)  d_in[0];
  const int*   neg_idx = (const int*)  d_in[1];
  const float* embed_W = (const float*)d_in[2];
  const float* embed_g = (const float*)d_in[3];
  const float* embed_b = (const float*)d_in[4];
  const float* proj_W  = (const float*)d_in[5];
  const float* proj_b  = (const float*)d_in[6];
  const float* qkv_W   = (const float*)d_in[7];
  const float* qkv_b   = (const float*)d_in[8];
  const float* ao_W    = (const float*)d_in[9];
  const float* ao_b    = (const float*)d_in[10];
  const float* ln1_g   = (const float*)d_in[11];
  const float* ln1_b   = (const float*)d_in[12];
  const float* ff1_W   = (const float*)d_in[13];
  const float* ff1_b   = (const float*)d_in[14];
  const float* ff2_W   = (const float*)d_in[15];
  const float* ff2_b   = (const float*)d_in[16];
  const float* ln2_g   = (const float*)d_in[17];
  const float* ln2_b   = (const float*)d_in[18];
  const float* head_W  = (const float*)d_in[19];
  const float* head_b  = (const float*)d_in[20];
  const float* head_g  = (const float*)d_in[21];
  const float* head_bt = (const float*)d_in[22];
  const float* oemb_W  = (const float*)d_in[23];
  const float* oemb_g  = (const float*)d_in[24];
  const float* oemb_b  = (const float*)d_in[25];
  float* out = (float*)d_out;

  char* ws = (char*)d_ws;
  size_t off = 0;
  auto alloc = [&](size_t bytes) -> char* {
    char* p = ws + off;
    off += (bytes + 255) & ~(size_t)255;
    return p;
  };
  bf16* wt_qkv  = (bf16*)alloc((size_t)2304 * 768 * 2);
  bf16* wt_ao   = (bf16*)alloc((size_t)768 * 768 * 2);
  bf16* wt_ff1  = (bf16*)alloc((size_t)3072 * 768 * 2);
  bf16* wt_ff2  = (bf16*)alloc((size_t)768 * 3072 * 2);
  bf16* wt_proj = (bf16*)alloc((size_t)768 * 128 * 2);
  bf16* wt_head = (bf16*)alloc((size_t)128 * 768 * 2);
  bf16* zbuf    = (bf16*)alloc((size_t)M_TOK * 128 * 2);
  bf16* x       = (bf16*)alloc((size_t)M_TOK * 768 * 2);
  bf16* big     = (bf16*)alloc((size_t)M_TOK * 3072 * 2);  // qkv, then h
  bf16* ctx     = (bf16*)alloc((size_t)M_TOK * 768 * 2);
  bf16* ybuf    = (bf16*)alloc((size_t)M_TOK * 768 * 2);
  bf16* p0      = (bf16*)alloc((size_t)M_TOK * 128 * 2);
  bf16* preds   = (bf16*)alloc((size_t)M_TOK * 128 * 2);
  bf16* outz    = (bf16*)alloc((size_t)M_TOK * 128 * 2);
  bf16* nege    = (bf16*)alloc((size_t)M_TOK * 128 * 2);

  const dim3 tb(32, 8);

  convtrans<<<dim3(768 / 32, 128 / 32), tb, 0, stream>>>(proj_W, wt_proj, 128, 768);
  convtrans<<<dim3(128 / 32, 768 / 32), tb, 0, stream>>>(head_W, wt_head, 768, 128);

  gather_ln128<<<M_TOK / 4, 256, 0, stream>>>(seq, embed_W, embed_g, embed_b, zbuf);
  gemm_bt<<<dim3(768 / 128, M_TOK / 128), 256, 0, stream>>>(zbuf, wt_proj, proj_b, x,
                                                            M_TOK, 768, 128, 2);

  for (int l = 0; l < LAYERS_; ++l) {
    convtrans<<<dim3(2304 / 32, 768 / 32), tb, 0, stream>>>(qkv_W + (size_t)l * 768 * 2304, wt_qkv, 768, 2304);
    convtrans<<<dim3(768 / 32, 768 / 32), tb, 0, stream>>>(ao_W + (size_t)l * 768 * 768, wt_ao, 768, 768);
    convtrans<<<dim3(3072 / 32, 768 / 32), tb, 0, stream>>>(ff1_W + (size_t)l * 768 * 3072, wt_ff1, 768, 3072);
    convtrans<<<dim3(768 / 32, 3072 / 32), tb, 0, stream>>>(ff2_W + (size_t)l * 3072 * 768, wt_ff2, 3072, 768);

    gemm256p<<<256, 512, 0, stream>>>(x, wt_qkv, qkv_b + l * 2304, big, M_TOK, 2304, 768, 0);
    attn_kernel<<<B_ * HEADS_, 128, 0, stream>>>(big, ctx);
    gemm256p<<<256, 512, 0, stream>>>(ctx, wt_ao, ao_b + l * 768, ybuf, M_TOK, 768, 768, 0);
    add_ln_kernel<<<M_TOK, 256, 0, stream>>>(x, ybuf, ln1_g + l * 768, ln1_b + l * 768, x);
    gemm256p<<<256, 512, 0, stream>>>(x, wt_ff1, ff1_b + l * 3072, big, M_TOK, 3072, 768, 1);
    gemm256p<<<256, 512, 0, stream>>>(big, wt_ff2, ff2_b + l * 768, ybuf, M_TOK, 768, 3072, 0);
    add_ln_kernel<<<M_TOK, 256, 0, stream>>>(x, ybuf, ln2_g + l * 768, ln2_b + l * 768, x);
  }

  gemm_bt<<<dim3(1, M_TOK / 128), 256, 0, stream>>>(x, wt_head, head_b, p0, M_TOK, 128, 768, 0);
  ln128_bf16<<<M_TOK / 4, 256, 0, stream>>>(p0, head_g, head_bt, preds);
  gather_ln128<<<M_TOK / 4, 256, 0, stream>>>(seq, oemb_W, oemb_g, oemb_b, outz);
  gather_ln128<<<M_TOK / 4, 256, 0, stream>>>(neg_idx, oemb_W, oemb_g, oemb_b, nege);
  zero_kernel<<<1, 1, 0, stream>>>(out);
  loss_kernel<<<dim3(B_, 2), 256, 0, stream>>>(outz, preds, nege, out);
}